// Round 3
// baseline (124.434 us; speedup 1.0000x reference)
//
#include <hip/hip_runtime.h>

// Problem constants (fixed by setup_inputs): B=4096, D=512, H=W=64, N=4096.
#define B_ROWS 4096
#define N_COLS 4096
#define DIM    512
#define LDK    1024   // row stride (elements) of split bf16 arrays [hi(512) | lo(512)]

typedef __attribute__((ext_vector_type(8))) short short8;
typedef __attribute__((ext_vector_type(4))) float floatx4;

// bf16 round-to-nearest-even split helpers (bit-exact, no API dependence)
__device__ __forceinline__ unsigned short f2bf_rn(float f) {
    unsigned u = __float_as_uint(f);
    u += 0x7fffu + ((u >> 16) & 1u);
    return (unsigned short)(u >> 16);
}
__device__ __forceinline__ float bf2f(unsigned short h) {
    return __uint_as_float(((unsigned)h) << 16);
}

// Monotone float->uint map; (key<<32)|idx gives u64 atomicMin argmin with
// smallest-index tie-break (matches numpy argmin semantics).
__device__ __forceinline__ unsigned long long pack_key(float v, int idx) {
    unsigned u = __float_as_uint(v);
    u = (u & 0x80000000u) ? ~u : (u | 0x80000000u);
    return ((unsigned long long)u << 32) | (unsigned)idx;
}

// Async global->LDS, 16B per lane. LDS dest is wave-uniform base + lane*16.
__device__ __forceinline__ void async16(const unsigned short* g, unsigned short* l) {
    __builtin_amdgcn_global_load_lds(
        (__attribute__((address_space(1))) void*)g,
        (__attribute__((address_space(3))) void*)l, 16, 0, 0);
}

// One wave per row (4 rows/block): split fp32 row into bf16 hi/lo halves,
// compute exact fp32 ||row||^2, init packed argmin accumulators.
// (16B stores this round — minor.)
__global__ __launch_bounds__(256) void som_convert(
    const float* __restrict__ X, const float* __restrict__ Wt,
    unsigned short* __restrict__ Xc, unsigned short* __restrict__ Wc,
    float* __restrict__ x_sq, float* __restrict__ w_sq,
    unsigned long long* __restrict__ packed)
{
    int wave = threadIdx.x >> 6, lane = threadIdx.x & 63;
    int grow = blockIdx.x * 4 + wave;            // 0..8191
    bool isX = grow < B_ROWS;
    const float* src = isX ? (X + (size_t)grow * DIM)
                           : (Wt + (size_t)(grow - B_ROWS) * DIM);
    const float4* p4 = (const float4*)src;
    float4 a = p4[lane * 2], b = p4[lane * 2 + 1];
    float f[8] = {a.x, a.y, a.z, a.w, b.x, b.y, b.z, b.w};
    short8 hi, lo;
    float s = 0.f;
    #pragma unroll
    for (int t = 0; t < 8; ++t) {
        unsigned short h = f2bf_rn(f[t]);
        hi[t] = (short)h;
        lo[t] = (short)f2bf_rn(f[t] - bf2f(h));
        s = fmaf(f[t], f[t], s);
    }
    unsigned short* dst = (isX ? Xc + (size_t)grow * LDK
                               : Wc + (size_t)(grow - B_ROWS) * LDK) + lane * 8;
    *(short8*)(dst)       = hi;
    *(short8*)(dst + 512) = lo;
    #pragma unroll
    for (int off = 32; off >= 1; off >>= 1) s += __shfl_xor(s, off, 64);
    if (lane == 0) {
        if (isX) { x_sq[grow] = s; packed[grow] = ~0ull; }
        else     { w_sq[grow - B_ROWS] = s; }
    }
}

// ---------------------------------------------------------------------------
// Split-bf16 distance GEMM v4: faithful m201-style 8-phase schedule.
// Geometry identical to v3 (256x256 tile, 8 waves 2x4, BK=32, 128KB dbuf,
// fragment-order subtiles => 0 bank conflicts, XCD swizzle). Per K-step:
// 6 phases of {<=8 ds_read_b128 ; <=4 global_load_lds ; s_barrier ; lgkm0 ;
// setprio(1) 16 MFMA setprio(0) ; s_barrier}; vmcnt(0) only at the tile
// boundary (stage of kt+1 issued Ph1-2, consumed next iter => ~64 MFMAs of
// cover). NO "memory" clobbers inside the loop (the v3 mistake): the
// scheduler interleaves ds_read/MFMA; raw barriers bound motion; one
// sched_barrier(0) per iteration pins the buffer epoch at the gate.
// Per-acc product order unchanged (hh, h*bl, al*h; kt ascending) => bit-exact.
// ---------------------------------------------------------------------------
#define PH_TAIL(MF)                                            \
    __builtin_amdgcn_s_barrier();                              \
    asm volatile("s_waitcnt lgkmcnt(0)");                      \
    __builtin_amdgcn_s_setprio(1);                             \
    MF                                                         \
    __builtin_amdgcn_s_setprio(0);                             \
    __builtin_amdgcn_s_barrier();

#define MFMA16(AF, BF, I0)                                     \
    _Pragma("unroll")                                          \
    for (int i = 0; i < 4; ++i)                                \
        _Pragma("unroll")                                      \
        for (int j = 0; j < 4; ++j)                            \
            acc[(I0) + i][j] = __builtin_amdgcn_mfma_f32_16x16x32_bf16( \
                AF[i], BF[j], acc[(I0) + i][j], 0, 0, 0);

__global__ __launch_bounds__(512, 2) void som_dist_v4(
    const unsigned short* __restrict__ Xc, const unsigned short* __restrict__ Wc,
    const float* __restrict__ w_sq, unsigned long long* __restrict__ packed)
{
    __shared__ __align__(16) unsigned short L[2 * 64 * 512];   // 128 KiB
    const int tid  = threadIdx.x;
    const int wave = tid >> 6, lane = tid & 63;
    const int quad = lane >> 4, t16 = lane & 15;
    const int wr = wave >> 2, wc = wave & 3;       // 2x4 wave grid (128x64 out/wave)

    // XCD-aware bijective swizzle: 256 blocks -> 8 XCDs x (8x4 rectangle).
    const int bid = blockIdx.y * 16 + blockIdx.x;  // 0..255
    const int xcd = bid & 7, wix = bid >> 3;       // wix 0..31
    const int bm = (xcd >> 2) * 8 + (wix & 7);
    const int bn = (xcd & 3) * 4 + (wix >> 3);

    // Staging role: waves 0-3 stage A (X), waves 4-7 stage B (W).
    // Wave sg stages row-blocks sg*4+q (q=0..3), both halves, 1KB subtiles.
    const int sg = wave & 3;
    const bool stB = (wave >= 4);
    const unsigned short* gsrc =
        (stB ? Wc + (size_t)bn * 256 * LDK : Xc + (size_t)bm * 256 * LDK)
        + (size_t)(sg * 64 + t16) * LDK + quad * 8;
    unsigned short* const lwav = &L[(stB ? 16384 : 0) + sg * 4096];

    // Fragment read bases (subtile-linear: lane*16B => conflict-free).
    // A subtile r (0..15) half h at offset (r*1024 + h*512); B at +16384.
    const unsigned short* const pA = &L[wr * 8192 + lane * 8];
    const unsigned short* const pB = &L[16384 + wc * 4096 + lane * 8];

    floatx4 acc[8][4];
    #pragma unroll
    for (int i = 0; i < 8; ++i)
        #pragma unroll
        for (int j = 0; j < 4; ++j) acc[i][j] = (floatx4){0.f, 0.f, 0.f, 0.f};

    // Prologue: stage tile 0 into buffer 0, drain, sync.
    #pragma unroll
    for (int q = 0; q < 4; ++q) {
        async16(gsrc + q * 16 * LDK,       lwav + q * 1024);
        async16(gsrc + q * 16 * LDK + 512, lwav + q * 1024 + 512);
    }
    asm volatile("s_waitcnt vmcnt(0)");
    __builtin_amdgcn_s_barrier();
    __builtin_amdgcn_sched_barrier(0);

    #pragma unroll 1
    for (int kt = 0; kt < 16; ++kt) {
        const int cur = kt & 1;
        const unsigned short* pAc = pA + cur * 32768;
        const unsigned short* pBc = pB + cur * 32768;
        const bool st = (kt < 15);
        const unsigned short* gs = gsrc + (kt + 1) * 32;
        unsigned short* dst = lwav + (cur ^ 1) * 32768;

        short8 ah0[4], ah1[4], al0[4], al1[4], bh[4], bl[4];

        // ---- Ph1: read ah0, bh; stage q0,q1; MFMA ah0 x bh
        #pragma unroll
        for (int i = 0; i < 4; ++i) ah0[i] = *(const short8*)(pAc + i * 1024);
        #pragma unroll
        for (int j = 0; j < 4; ++j) bh[j]  = *(const short8*)(pBc + j * 1024);
        if (st) {
            async16(gs,                 dst);
            async16(gs + 512,           dst + 512);
            async16(gs + 16 * LDK,      dst + 1024);
            async16(gs + 16 * LDK + 512, dst + 1536);
        }
        PH_TAIL(MFMA16(ah0, bh, 0))

        // ---- Ph2: read bl; stage q2,q3; MFMA ah0 x bl
        #pragma unroll
        for (int j = 0; j < 4; ++j) bl[j] = *(const short8*)(pBc + j * 1024 + 512);
        if (st) {
            async16(gs + 32 * LDK,       dst + 2048);
            async16(gs + 32 * LDK + 512, dst + 2560);
            async16(gs + 48 * LDK,       dst + 3072);
            async16(gs + 48 * LDK + 512, dst + 3584);
        }
        PH_TAIL(MFMA16(ah0, bl, 0))

        // ---- Ph3: read al0; MFMA al0 x bh
        #pragma unroll
        for (int i = 0; i < 4; ++i) al0[i] = *(const short8*)(pAc + i * 1024 + 512);
        PH_TAIL(MFMA16(al0, bh, 0))

        // ---- Ph4: read ah1; MFMA ah1 x bh
        #pragma unroll
        for (int i = 0; i < 4; ++i) ah1[i] = *(const short8*)(pAc + (4 + i) * 1024);
        PH_TAIL(MFMA16(ah1, bh, 4))

        // ---- Ph5: read al1; MFMA ah1 x bl
        #pragma unroll
        for (int i = 0; i < 4; ++i) al1[i] = *(const short8*)(pAc + (4 + i) * 1024 + 512);
        PH_TAIL(MFMA16(ah1, bl, 4))

        // ---- Ph6: MFMA al1 x bh (pure-reg)
        asm volatile("s_waitcnt lgkmcnt(0)");
        __builtin_amdgcn_s_setprio(1);
        MFMA16(al1, bh, 4)
        __builtin_amdgcn_s_setprio(0);

        // ---- tile-boundary gate: tile kt+1 landed everywhere; all reads of
        // buf[cur] are register-retired; next iter may overwrite buf[cur].
        asm volatile("s_waitcnt vmcnt(0)");
        __builtin_amdgcn_s_barrier();
        __builtin_amdgcn_sched_barrier(0);
    }

    // Epilogue: val = w_sq - 2*dot (x_sq is per-row constant, irrelevant to
    // argmin). C/D layout: col = t16, row = quad*4 + reg  [m89/m91].
    const int col0 = bn * 256 + wc * 64 + t16;
    float wq[4];
    #pragma unroll
    for (int j = 0; j < 4; ++j) wq[j] = w_sq[col0 + j * 16];
    const int row_base = bm * 256 + wr * 128 + quad * 4;
    #pragma unroll
    for (int i = 0; i < 8; ++i) {
        #pragma unroll
        for (int r = 0; r < 4; ++r) {
            unsigned long long best = ~0ull;
            #pragma unroll
            for (int j = 0; j < 4; ++j) {
                float val = fmaf(-2.f, acc[i][j][r], wq[j]);
                unsigned long long key = pack_key(val, col0 + j * 16);
                best = (key < best) ? key : best;
            }
            #pragma unroll
            for (int m = 1; m <= 8; m <<= 1) {     // reduce 16-lane col group
                unsigned long long o = __shfl_xor(best, m, 64);
                best = (o < best) ? o : best;
            }
            if (t16 == 0)
                atomicMin(&packed[row_base + i * 16 + r], best);
        }
    }
}

// Unpack argmin, qe = sqrt(max(||x||^2 + val, 0)).
// d_out: bmu_indices (4096 x 2) flat, then qe (4096), all float. (unchanged)
__global__ __launch_bounds__(256) void som_finalize(
    const unsigned long long* __restrict__ packed,
    const float* __restrict__ x_sq, float* __restrict__ out)
{
    int b = blockIdx.x * 256 + threadIdx.x;  // 0..4095
    unsigned long long p = packed[b];
    unsigned idx = (unsigned)(p & 0xffffffffull);
    unsigned key = (unsigned)(p >> 32);
    unsigned u = (key & 0x80000000u) ? (key & 0x7fffffffu) : ~key;
    float val = __uint_as_float(u);
    float sq = fmaxf(x_sq[b] + val, 0.f);
    out[2 * b]     = (float)(idx >> 6);   // y = idx / 64
    out[2 * b + 1] = (float)(idx & 63);   // x = idx % 64
    out[2 * B_ROWS + b] = sqrtf(sq);
}

extern "C" void kernel_launch(void* const* d_in, const int* in_sizes, int n_in,
                              void* d_out, int out_size, void* d_ws, size_t ws_size,
                              hipStream_t stream) {
    const float* X  = (const float*)d_in[0];   // (4096, 512)
    const float* Wt = (const float*)d_in[1];   // (64, 64, 512) -> (4096, 512)
    float* out = (float*)d_out;

    // ws layout: [0,32K) packed u64[4096]; [32K,48K) x_sq; [48K,64K) w_sq;
    // [64K, 64K+8M) Xc bf16 split; [64K+8M, 64K+16M) Wc bf16 split.
    unsigned long long* packed = (unsigned long long*)d_ws;
    float* x_sq = (float*)((char*)d_ws + (32 << 10));
    float* w_sq = (float*)((char*)d_ws + (48 << 10));
    unsigned short* Xc = (unsigned short*)((char*)d_ws + (64 << 10));
    unsigned short* Wc = (unsigned short*)((char*)d_ws + (64 << 10) + ((size_t)B_ROWS * LDK * 2));

    som_convert<<<dim3((B_ROWS + N_COLS) / 4), dim3(256), 0, stream>>>(
        X, Wt, Xc, Wc, x_sq, w_sq, packed);
    som_dist_v4<<<dim3(N_COLS / 256, B_ROWS / 256), dim3(512), 0, stream>>>(
        Xc, Wc, w_sq, packed);
    som_finalize<<<dim3(B_ROWS / 256), dim3(256), 0, stream>>>(packed, x_sq, out);
}

// Round 4
// 116.694 us; speedup vs baseline: 1.0663x; 1.0663x over previous
//
#include <hip/hip_runtime.h>

// Problem constants (fixed by setup_inputs): B=4096, D=512, H=W=64, N=4096.
#define B_ROWS 4096
#define N_COLS 4096
#define DIM    512
#define LDK    1024   // row stride (elements) of split bf16 arrays [hi(512) | lo(512)]

typedef __attribute__((ext_vector_type(8))) short short8;
typedef __attribute__((ext_vector_type(4))) float floatx4;

// bf16 round-to-nearest-even split helpers (bit-exact, no API dependence)
__device__ __forceinline__ unsigned short f2bf_rn(float f) {
    unsigned u = __float_as_uint(f);
    u += 0x7fffu + ((u >> 16) & 1u);
    return (unsigned short)(u >> 16);
}
__device__ __forceinline__ float bf2f(unsigned short h) {
    return __uint_as_float(((unsigned)h) << 16);
}

// Monotone float->uint map; (key<<32)|idx gives u64 atomicMin argmin with
// smallest-index tie-break (matches numpy argmin semantics).
__device__ __forceinline__ unsigned long long pack_key(float v, int idx) {
    unsigned u = __float_as_uint(v);
    u = (u & 0x80000000u) ? ~u : (u | 0x80000000u);
    return ((unsigned long long)u << 32) | (unsigned)idx;
}

// Async global->LDS, 16B per lane. LDS dest is wave-uniform base + lane*16.
__device__ __forceinline__ void async16(const unsigned short* g, unsigned short* l) {
    __builtin_amdgcn_global_load_lds(
        (__attribute__((address_space(1))) void*)g,
        (__attribute__((address_space(3))) void*)l, 16, 0, 0);
}

// One wave per row (4 rows/block): split fp32 row into bf16 hi/lo halves,
// compute exact fp32 ||row||^2, init packed argmin accumulators. (unchanged)
__global__ __launch_bounds__(256) void som_convert(
    const float* __restrict__ X, const float* __restrict__ Wt,
    unsigned short* __restrict__ Xc, unsigned short* __restrict__ Wc,
    float* __restrict__ x_sq, float* __restrict__ w_sq,
    unsigned long long* __restrict__ packed)
{
    int wave = threadIdx.x >> 6, lane = threadIdx.x & 63;
    int grow = blockIdx.x * 4 + wave;            // 0..8191
    bool isX = grow < B_ROWS;
    const float* src = isX ? (X + (size_t)grow * DIM)
                           : (Wt + (size_t)(grow - B_ROWS) * DIM);
    const float4* p4 = (const float4*)src;
    float4 a = p4[lane * 2], b = p4[lane * 2 + 1];
    float f[8] = {a.x, a.y, a.z, a.w, b.x, b.y, b.z, b.w};
    short8 hi, lo;
    float s = 0.f;
    #pragma unroll
    for (int t = 0; t < 8; ++t) {
        unsigned short h = f2bf_rn(f[t]);
        hi[t] = (short)h;
        lo[t] = (short)f2bf_rn(f[t] - bf2f(h));
        s = fmaf(f[t], f[t], s);
    }
    unsigned short* dst = (isX ? Xc + (size_t)grow * LDK
                               : Wc + (size_t)(grow - B_ROWS) * LDK) + lane * 8;
    *(short8*)(dst)       = hi;
    *(short8*)(dst + 512) = lo;
    #pragma unroll
    for (int off = 32; off >= 1; off >>= 1) s += __shfl_xor(s, off, 64);
    if (lane == 0) {
        if (isX) { x_sq[grow] = s; packed[grow] = ~0ull; }
        else     { w_sq[grow - B_ROWS] = s; }
    }
}

// ---------------------------------------------------------------------------
// Split-bf16 distance GEMM v5 = v4's 6-phase schedule + T4 counted vmcnt.
// Stage order per wave per K-tile: 4 hi loads first (Ph1: q0h,q1h; Ph2:
// q2h,q3h), then 4 lo loads (Ph3: q0l,q1l; Ph4: q2l,q3l). Gates:
//   GATE-H (iter top): vmcnt(4)  -> hi(kt) done, lo(kt) still in flight
//   GATE-L (after Ph1): vmcnt(2) -> lo(kt) done, hi(kt+1) pair in flight
// vmcnt never drains to 0 in the main loop (only last iter's GATE-L).
// In-order vmcnt retirement [m135] makes the counts exact; sched_barrier(0)
// at each gate pins load-issue order at compile time. Buffer hazard: writes
// to buf[cur^1] are issued only after the barrier that follows every wave's
// lgkmcnt(0)-retired reads of that buffer. Per-acc product order unchanged
// (hh, h*bl, al*h; kt ascending) => bit-exact vs v1-v4.
// ---------------------------------------------------------------------------
#define PH_CORE(MF)                                            \
    __builtin_amdgcn_s_barrier();                              \
    asm volatile("s_waitcnt lgkmcnt(0)");                      \
    __builtin_amdgcn_s_setprio(1);                             \
    MF                                                         \
    __builtin_amdgcn_s_setprio(0);

#define MFMA16(AF, BF, I0)                                     \
    _Pragma("unroll")                                          \
    for (int i = 0; i < 4; ++i)                                \
        _Pragma("unroll")                                      \
        for (int j = 0; j < 4; ++j)                            \
            acc[(I0) + i][j] = __builtin_amdgcn_mfma_f32_16x16x32_bf16( \
                AF[i], BF[j], acc[(I0) + i][j], 0, 0, 0);

__global__ __launch_bounds__(512, 2) void som_dist_v5(
    const unsigned short* __restrict__ Xc, const unsigned short* __restrict__ Wc,
    const float* __restrict__ w_sq, unsigned long long* __restrict__ packed)
{
    __shared__ __align__(16) unsigned short L[2 * 64 * 512];   // 128 KiB
    const int tid  = threadIdx.x;
    const int wave = tid >> 6, lane = tid & 63;
    const int quad = lane >> 4, t16 = lane & 15;
    const int wr = wave >> 2, wc = wave & 3;       // 2x4 wave grid (128x64 out/wave)

    // XCD-aware bijective swizzle: 256 blocks -> 8 XCDs x (8x4 rectangle).
    const int bid = blockIdx.y * 16 + blockIdx.x;  // 0..255
    const int xcd = bid & 7, wix = bid >> 3;       // wix 0..31
    const int bm = (xcd >> 2) * 8 + (wix & 7);
    const int bn = (xcd & 3) * 4 + (wix >> 3);

    // Staging role: waves 0-3 stage A (X), waves 4-7 stage B (W).
    const int sg = wave & 3;
    const bool stB = (wave >= 4);
    const unsigned short* gsrc =
        (stB ? Wc + (size_t)bn * 256 * LDK : Xc + (size_t)bm * 256 * LDK)
        + (size_t)(sg * 64 + t16) * LDK + quad * 8;
    unsigned short* const lwav = &L[(stB ? 16384 : 0) + sg * 4096];

    // Fragment read bases (subtile-linear: lane*16B => conflict-free).
    const unsigned short* const pA = &L[wr * 8192 + lane * 8];
    const unsigned short* const pB = &L[16384 + wc * 4096 + lane * 8];

    floatx4 acc[8][4];
    #pragma unroll
    for (int i = 0; i < 8; ++i)
        #pragma unroll
        for (int j = 0; j < 4; ++j) acc[i][j] = (floatx4){0.f, 0.f, 0.f, 0.f};

    // Prologue: stage tile 0, hi loads first then lo (same order as loop).
    #pragma unroll
    for (int q = 0; q < 4; ++q) async16(gsrc + q * 16 * LDK, lwav + q * 1024);
    #pragma unroll
    for (int q = 0; q < 4; ++q) async16(gsrc + q * 16 * LDK + 512, lwav + q * 1024 + 512);
    asm volatile("s_waitcnt vmcnt(4)");            // hi(0) ready; lo(0) in flight
    __builtin_amdgcn_sched_barrier(0);
    __builtin_amdgcn_s_barrier();

    #pragma unroll 1
    for (int kt = 0; kt < 16; ++kt) {
        const int cur = kt & 1;
        const unsigned short* pAc = pA + cur * 32768;
        const unsigned short* pBc = pB + cur * 32768;
        const bool st = (kt < 15);
        const unsigned short* gs = gsrc + (kt + 1) * 32;
        unsigned short* dst = lwav + (cur ^ 1) * 32768;

        short8 ah0[4], ah1[4], al0[4], al1[4], bh[4], bl[4];

        // ---- Ph1 (hi(kt) valid): read ah0, bh; stage q0h,q1h(kt+1)
        #pragma unroll
        for (int i = 0; i < 4; ++i) ah0[i] = *(const short8*)(pAc + i * 1024);
        #pragma unroll
        for (int j = 0; j < 4; ++j) bh[j]  = *(const short8*)(pBc + j * 1024);
        if (st) {
            async16(gs,            dst);
            async16(gs + 16 * LDK, dst + 1024);
        }
        PH_CORE(MFMA16(ah0, bh, 0))
        // GATE-L: lo(kt) done (2 newest = hi(kt+1) pair stay in flight)
        if (kt == 15) asm volatile("s_waitcnt vmcnt(0)");
        else          asm volatile("s_waitcnt vmcnt(2)");
        __builtin_amdgcn_sched_barrier(0);
        __builtin_amdgcn_s_barrier();

        // ---- Ph2: read bl; stage q2h,q3h
        #pragma unroll
        for (int j = 0; j < 4; ++j) bl[j] = *(const short8*)(pBc + j * 1024 + 512);
        if (st) {
            async16(gs + 32 * LDK, dst + 2048);
            async16(gs + 48 * LDK, dst + 3072);
        }
        PH_CORE(MFMA16(ah0, bl, 0))
        __builtin_amdgcn_s_barrier();

        // ---- Ph3: read al0; stage q0l,q1l
        #pragma unroll
        for (int i = 0; i < 4; ++i) al0[i] = *(const short8*)(pAc + i * 1024 + 512);
        if (st) {
            async16(gs + 512,            dst + 512);
            async16(gs + 16 * LDK + 512, dst + 1536);
        }
        PH_CORE(MFMA16(al0, bh, 0))
        __builtin_amdgcn_s_barrier();

        // ---- Ph4: read ah1; stage q2l,q3l
        #pragma unroll
        for (int i = 0; i < 4; ++i) ah1[i] = *(const short8*)(pAc + (4 + i) * 1024);
        if (st) {
            async16(gs + 32 * LDK + 512, dst + 2560);
            async16(gs + 48 * LDK + 512, dst + 3584);
        }
        PH_CORE(MFMA16(ah1, bh, 4))
        __builtin_amdgcn_s_barrier();

        // ---- Ph5: read al1
        #pragma unroll
        for (int i = 0; i < 4; ++i) al1[i] = *(const short8*)(pAc + (4 + i) * 1024 + 512);
        PH_CORE(MFMA16(ah1, bl, 4))
        __builtin_amdgcn_s_barrier();

        // ---- Ph6: pure-reg MFMA
        asm volatile("s_waitcnt lgkmcnt(0)");
        __builtin_amdgcn_s_setprio(1);
        MFMA16(al1, bh, 4)
        __builtin_amdgcn_s_setprio(0);

        // GATE-H: hi(kt+1) done (4 lo(kt+1) loads stay in flight); also the
        // barrier after which buf[cur] may be overwritten (all reads retired).
        asm volatile("s_waitcnt vmcnt(4)");
        __builtin_amdgcn_sched_barrier(0);
        __builtin_amdgcn_s_barrier();
    }

    // Epilogue: val = w_sq - 2*dot (x_sq is per-row constant, irrelevant to
    // argmin). C/D layout: col = t16, row = quad*4 + reg  [m89/m91].
    const int col0 = bn * 256 + wc * 64 + t16;
    float wq[4];
    #pragma unroll
    for (int j = 0; j < 4; ++j) wq[j] = w_sq[col0 + j * 16];
    const int row_base = bm * 256 + wr * 128 + quad * 4;
    #pragma unroll
    for (int i = 0; i < 8; ++i) {
        #pragma unroll
        for (int r = 0; r < 4; ++r) {
            unsigned long long best = ~0ull;
            #pragma unroll
            for (int j = 0; j < 4; ++j) {
                float val = fmaf(-2.f, acc[i][j][r], wq[j]);
                unsigned long long key = pack_key(val, col0 + j * 16);
                best = (key < best) ? key : best;
            }
            #pragma unroll
            for (int m = 1; m <= 8; m <<= 1) {     // reduce 16-lane col group
                unsigned long long o = __shfl_xor(best, m, 64);
                best = (o < best) ? o : best;
            }
            if (t16 == 0)
                atomicMin(&packed[row_base + i * 16 + r], best);
        }
    }
}

// Unpack argmin, qe = sqrt(max(||x||^2 + val, 0)).
// d_out: bmu_indices (4096 x 2) flat, then qe (4096), all float. (unchanged)
__global__ __launch_bounds__(256) void som_finalize(
    const unsigned long long* __restrict__ packed,
    const float* __restrict__ x_sq, float* __restrict__ out)
{
    int b = blockIdx.x * 256 + threadIdx.x;  // 0..4095
    unsigned long long p = packed[b];
    unsigned idx = (unsigned)(p & 0xffffffffull);
    unsigned key = (unsigned)(p >> 32);
    unsigned u = (key & 0x80000000u) ? (key & 0x7fffffffu) : ~key;
    float val = __uint_as_float(u);
    float sq = fmaxf(x_sq[b] + val, 0.f);
    out[2 * b]     = (float)(idx >> 6);   // y = idx / 64
    out[2 * b + 1] = (float)(idx & 63);   // x = idx % 64
    out[2 * B_ROWS + b] = sqrtf(sq);
}

extern "C" void kernel_launch(void* const* d_in, const int* in_sizes, int n_in,
                              void* d_out, int out_size, void* d_ws, size_t ws_size,
                              hipStream_t stream) {
    const float* X  = (const float*)d_in[0];   // (4096, 512)
    const float* Wt = (const float*)d_in[1];   // (64, 64, 512) -> (4096, 512)
    float* out = (float*)d_out;

    // ws layout: [0,32K) packed u64[4096]; [32K,48K) x_sq; [48K,64K) w_sq;
    // [64K, 64K+8M) Xc bf16 split; [64K+8M, 64K+16M) Wc bf16 split.
    unsigned long long* packed = (unsigned long long*)d_ws;
    float* x_sq = (float*)((char*)d_ws + (32 << 10));
    float* w_sq = (float*)((char*)d_ws + (48 << 10));
    unsigned short* Xc = (unsigned short*)((char*)d_ws + (64 << 10));
    unsigned short* Wc = (unsigned short*)((char*)d_ws + (64 << 10) + ((size_t)B_ROWS * LDK * 2));

    som_convert<<<dim3((B_ROWS + N_COLS) / 4), dim3(256), 0, stream>>>(
        X, Wt, Xc, Wc, x_sq, w_sq, packed);
    som_dist_v5<<<dim3(N_COLS / 256, B_ROWS / 256), dim3(512), 0, stream>>>(
        Xc, Wc, w_sq, packed);
    som_finalize<<<dim3(B_ROWS / 256), dim3(256), 0, stream>>>(packed, x_sq, out);
}